// Round 6
// baseline (594.206 us; speedup 1.0000x reference)
//
#include <hip/hip_runtime.h>
#include <hip/hip_fp16.h>

// DGCF single-layer, 2 routing iters (MI355X). fp32 in / fp32 out.
// R5 post-mortem: fused0/fused1 bound by random 128B row-gathers missing L2
// (FETCH 154MB ~= dur * BW; tables 15.4MB >> 4MB/XCD L2).
// R6: channel-sliced tables [intent][N][16] (1.92MB/slice) + intent->XCD
// pinning via blockIdx%8 so each XCD's working set (~3.8MB) is L2-resident.
// Cross-intent softmax split into an edge-parallel kernel over a v[E][4]
// dot buffer. Per-edge shuffle cost drops 8 -> ~1 (4 edges reduced at once).

#define NUSERS 30000
#define NN     60000
#define EE     800000
#define SL     ((size_t)NN * 16)   // elements per intent slice

__device__ __forceinline__ float getX(const float* __restrict__ Gu,
                                      const float* __restrict__ Gi,
                                      int n, int c) {
    return (n < NUSERS) ? Gu[n * 64 + c] : Gi[(n - NUSERS) * 64 + c];
}

__device__ __forceinline__ int clampN(int n) {
    return ((unsigned)n < (unsigned)NN) ? n : 0;
}

// ---- CSR build ----

__global__ void edge_count(const int* __restrict__ eh, int* __restrict__ deg0) {
    int e = blockIdx.x * blockDim.x + threadIdx.x;
    if (e >= EE) return;
    atomicAdd(&deg0[clampN(eh[e])], 1);
}

__global__ void scan_offsets(const int* __restrict__ deg0, int* __restrict__ offsets) {
    __shared__ int sums[1024];
    const int CH = (NN + 1023) / 1024;
    int tid = threadIdx.x;
    int base = tid * CH;
    int s = 0;
    for (int j = 0; j < CH; ++j) {
        int idx = base + j;
        if (idx < NN) s += deg0[idx];
    }
    sums[tid] = s;
    __syncthreads();
    for (int off = 1; off < 1024; off <<= 1) {
        int v = (tid >= off) ? sums[tid - off] : 0;
        __syncthreads();
        sums[tid] += v;
        __syncthreads();
    }
    int run = (tid == 0) ? 0 : sums[tid - 1];
    for (int j = 0; j < CH; ++j) {
        int idx = base + j;
        if (idx < NN) { offsets[idx] = run; run += deg0[idx]; }
    }
    if (tid == 1023) offsets[NN] = sums[1023];
}

__global__ void edge_scatter(const int* __restrict__ eh, const int* __restrict__ et,
                             const int* __restrict__ offsets, int* __restrict__ cursor,
                             int* __restrict__ csr_tail) {
    int e = blockIdx.x * blockDim.x + threadIdx.x;
    if (e >= EE) return;
    int h = clampN(eh[e]);
    int slot = offsets[h] + atomicAdd(&cursor[h], 1);
    if (slot < EE) csr_tail[slot] = clampN(et[e]);
}

// ---- node-side precompute (sliced layouts) ----

// Wave/node: Tns[i][n][ch] = tanh(x/|x|_i), Ys[i][n][ch] = dcol0*x  (fp16)
__global__ void prep0s(const float* __restrict__ Gu, const float* __restrict__ Gi,
                       const int* __restrict__ deg0,
                       __half* __restrict__ Tns, __half* __restrict__ Ys) {
    int n = blockIdx.x * 4 + (threadIdx.x >> 6);
    if (n >= NN) return;
    int lane = threadIdx.x & 63;
    int i = lane >> 4, ch = lane & 15;
    float x = getX(Gu, Gi, n, lane);
    float sx = x * x;
    #pragma unroll
    for (int m = 1; m < 16; m <<= 1) sx += __shfl_xor(sx, m, 64);
    float invx = rsqrtf(fmaxf(sx, 1e-12f));
    size_t a = (size_t)i * SL + (size_t)n * 16 + ch;
    Tns[a] = __float2half(tanhf(x * invx));
    float d0 = rsqrtf(fmaxf(0.25f * (float)deg0[n], 1e-30f));
    Ys[a] = __float2half(d0 * x);
}

// ---- intent-sliced, XCD-pinned edge passes ----
// Wave = one (node, intent); lanes = 4 edge-slots x 16 channels.
// blockIdx%8 = XCD; intent = xcd>>1 -> each intent's 1.92MB slices live
// on 2 XCDs' L2. Block = 4 waves = 4 nodes, same intent.

__global__ void dots_kernel(const int* __restrict__ offsets, const int* __restrict__ csr_tail,
                            const __half* __restrict__ Ys, const __half* __restrict__ Tns,
                            float* __restrict__ v) {
    int b = blockIdx.x;
    int xcd = b & 7;
    int i = xcd >> 1;
    int g = (b >> 3) * 2 + (xcd & 1);          // node group [0,15000)
    int n = g * 4 + (threadIdx.x >> 6);
    int lane = threadIdx.x & 63;
    int seg = lane >> 4, ch = lane & 15;
    int s0 = offsets[n], s1 = offsets[n + 1];
    const __half* Yi = Ys + (size_t)i * SL;
    const __half* Ti = Tns + (size_t)i * SL;

    float acc = 0.f;
    for (int k = s0; k < s1; k += 4) {
        int kk = k + seg;
        int t = (kk < s1) ? csr_tail[kk] : 0;
        float y = __half2float(Yi[(size_t)t * 16 + ch]);
        acc += (kk < s1) ? y : 0.f;
    }
    acc += __shfl_xor(acc, 16, 64);
    acc += __shfl_xor(acc, 32, 64);
    acc *= 0.25f;
    float sz = acc * acc;
    #pragma unroll
    for (int m = 1; m < 16; m <<= 1) sz += __shfl_xor(sz, m, 64);
    float zn = acc * rsqrtf(fmaxf(sz, 1e-12f));   // l2norm(Z1)_intent in regs

    for (int k = s0; k < s1; k += 4) {
        int kk = k + seg;
        int t = (kk < s1) ? csr_tail[kk] : 0;
        float p = zn * __half2float(Ti[(size_t)t * 16 + ch]);
        #pragma unroll
        for (int m = 1; m < 16; m <<= 1) p += __shfl_xor(p, m, 64);
        if (kk < s1 && ch == 0) v[(size_t)kk * 4 + i] = p;
    }
}

// Edge-parallel 4-way softmax: v[E][4] -> scores[E][4] fp16.
__global__ void softmax_kernel(const float* __restrict__ v, __half* __restrict__ scores) {
    int e = blockIdx.x * blockDim.x + threadIdx.x;
    if (e >= EE) return;
    float4 vv = ((const float4*)v)[e];
    float mx = fmaxf(fmaxf(vv.x, vv.y), fmaxf(vv.z, vv.w));
    float e0 = __expf(vv.x - mx), e1 = __expf(vv.y - mx);
    float e2 = __expf(vv.z - mx), e3 = __expf(vv.w - mx);
    float inv = 1.f / (e0 + e1 + e2 + e3);
    __half2* s2 = (__half2*)(scores + (size_t)e * 4);
    s2[0] = __floats2half2_rn(e0 * inv, e1 * inv);
    s2[1] = __floats2half2_rn(e2 * inv, e3 * inv);
}

// Wave/node: deg[n][i] = sum of scores over n's CSR segment -> dcol1.
__global__ void dcol1_kernel(const int* __restrict__ offsets, const __half* __restrict__ scores,
                             float* __restrict__ dcol1) {
    int n = blockIdx.x * 4 + (threadIdx.x >> 6);
    if (n >= NN) return;
    int lane = threadIdx.x & 63;
    int j = lane >> 2, i = lane & 3;
    int s0 = offsets[n], s1 = offsets[n + 1];
    float sum = 0.f;
    for (int k = s0 + j; k < s1; k += 16) sum += __half2float(scores[(size_t)k * 4 + i]);
    #pragma unroll
    for (int m = 4; m < 64; m <<= 1) sum += __shfl_xor(sum, m, 64);
    if (j == 0) dcol1[n * 4 + i] = rsqrtf(fmaxf(sum, 1e-30f));
}

// Y1s[i][n][ch] = dcol1[n][i] * X[n][i*16+ch]  (fp16, sliced)
__global__ void build_Y1s(const float* __restrict__ Gu, const float* __restrict__ Gi,
                          const float* __restrict__ dcol1, __half* __restrict__ Y1s) {
    int idx = blockIdx.x * blockDim.x + threadIdx.x;
    if (idx >= NN * 64) return;
    int i = idx / (NN * 16);
    int r = idx - i * (NN * 16);
    int n = r >> 4, ch = r & 15;
    Y1s[idx] = __float2half(dcol1[n * 4 + i] * getX(Gu, Gi, n, i * 16 + ch));
}

// Wave = (node, intent): Z2 slice gather -> out = 0.5*(x + dcol1*Z2).
__global__ void out_kernel(const int* __restrict__ offsets, const int* __restrict__ csr_tail,
                           const __half* __restrict__ Y1s, const __half* __restrict__ scores,
                           const float* __restrict__ dcol1,
                           const float* __restrict__ Gu, const float* __restrict__ Gi,
                           float* __restrict__ out) {
    int b = blockIdx.x;
    int xcd = b & 7;
    int i = xcd >> 1;
    int g = (b >> 3) * 2 + (xcd & 1);
    int n = g * 4 + (threadIdx.x >> 6);
    int lane = threadIdx.x & 63;
    int seg = lane >> 4, ch = lane & 15;
    int s0 = offsets[n], s1 = offsets[n + 1];
    const __half* Yi = Y1s + (size_t)i * SL;

    float acc = 0.f;
    for (int k = s0; k < s1; k += 4) {
        int kk = k + seg;
        int t = (kk < s1) ? csr_tail[kk] : 0;
        float s = (kk < s1) ? __half2float(scores[(size_t)kk * 4 + i]) : 0.f;
        acc += s * __half2float(Yi[(size_t)t * 16 + ch]);
    }
    acc += __shfl_xor(acc, 16, 64);
    acc += __shfl_xor(acc, 32, 64);
    if (seg == 0) {
        int c = i * 16 + ch;
        float x = getX(Gu, Gi, n, c);
        out[n * 64 + c] = 0.5f * (x + dcol1[n * 4 + i] * acc);
    }
}

// ---- launch ----

extern "C" void kernel_launch(void* const* d_in, const int* in_sizes, int n_in,
                              void* d_out, int out_size, void* d_ws, size_t ws_size,
                              hipStream_t stream) {
    const float* Gu = (const float*)d_in[0];
    const float* Gi = (const float*)d_in[1];
    const int* eh = (const int*)d_in[2];
    const int* et = (const int*)d_in[3];
    float* out = (float*)d_out;

    char* p = (char*)d_ws;
    float*  v        = (float*)p;      p += (size_t)EE * 4 * 4;       // 12.8 MB (16B aligned)
    __half* scores   = (__half*)p;     p += (size_t)EE * 4 * 2;       // 6.4 MB
    int*    csr_tail = (int*)p;        p += (size_t)EE * 4;           // 3.2 MB
    int*    offsets  = (int*)p;        p += ((size_t)(NN + 1) * 4 + 15) / 16 * 16;
    int*    deg0     = (int*)p;        p += (size_t)NN * 4;
    int*    cursor   = (int*)p;        p += (size_t)NN * 4;
    float*  dcol1    = (float*)p;      p += (size_t)NN * 4 * 4;
    __half* Ys       = (__half*)p;     p += 4 * SL * 2;               // 7.68 MB (Y1s reuses)
    __half* Tns      = (__half*)p;     // 7.68 MB  -> total ~39.4 MB (ws >= 46.7 proven in R4)
    __half* Y1s      = Ys;

    const int nk_blocks   = (NN * 64 + 255) / 256;
    const int edge_blocks = (EE + 255) / 256;
    const int nw_blocks   = (NN + 3) / 4;
    const int sl_blocks   = NN;        // 60000 blocks: 15000 groups x 4 intents

    // CSR build
    hipMemsetAsync(deg0, 0, NN * sizeof(int), stream);
    hipMemsetAsync(cursor, 0, NN * sizeof(int), stream);
    edge_count<<<edge_blocks, 256, 0, stream>>>(eh, deg0);
    scan_offsets<<<1, 1024, 0, stream>>>(deg0, offsets);
    edge_scatter<<<edge_blocks, 256, 0, stream>>>(eh, et, offsets, cursor, csr_tail);

    // iter 0: sliced tables + dots
    prep0s<<<nw_blocks, 256, 0, stream>>>(Gu, Gi, deg0, Tns, Ys);
    dots_kernel<<<sl_blocks, 256, 0, stream>>>(offsets, csr_tail, Ys, Tns, v);
    softmax_kernel<<<edge_blocks, 256, 0, stream>>>(v, scores);

    // iter 1: dcol1, sliced Y1, fused propagate+finalize
    dcol1_kernel<<<nw_blocks, 256, 0, stream>>>(offsets, scores, dcol1);
    build_Y1s<<<nk_blocks, 256, 0, stream>>>(Gu, Gi, dcol1, Y1s);
    out_kernel<<<sl_blocks, 256, 0, stream>>>(offsets, csr_tail, Y1s, scores, dcol1, Gu, Gi, out);
}